// Round 3
// baseline (309.790 us; speedup 1.0000x reference)
//
#include <hip/hip_runtime.h>
#include <hip/hip_bf16.h>

// Problem constants (from reference):
//   x: (B=16, N=256) int32, values in [0, 64)
//   pos_enc: (MAX_LEN=20000, EMBED_DIM=512) float32
//   out: (B, T, 512) float32, T = max row-total of x (recovered from out_size)
#define PB 16
#define PN 256
#define PD 512          // floats per row
#define PD4 128         // float4 per row
#define TCHUNK 64       // t-values per block

typedef float f32x4 __attribute__((ext_vector_type(4)));  // native vec: OK for nontemporal builtins

__global__ __launch_bounds__(256, 4)
void posenc_kernel(const int* __restrict__ x,
                   const float* __restrict__ pe,
                   float* __restrict__ out,
                   int T) {
    const int b   = blockIdx.y;
    const int t0  = blockIdx.x * TCHUNK;
    const int tid = threadIdx.x;            // 256 threads

    __shared__ int cum[PN];                 // inclusive cumsum of x[b, :]
    __shared__ int xs[PN];                  // x[b, :]
    __shared__ int posArr[TCHUNK];          // gathered pos per t, -1 = invalid (zero row)

    // Load this row's segment lengths and scan them in LDS.
    int v = x[b * PN + tid];
    xs[tid]  = v;
    cum[tid] = v;
    __syncthreads();

    // Hillis-Steele inclusive scan over 256 elements (8 steps).
    #pragma unroll
    for (int off = 1; off < PN; off <<= 1) {
        int add = (tid >= off) ? cum[tid - off] : 0;
        __syncthreads();
        cum[tid] += add;
        __syncthreads();
    }
    const int total = cum[PN - 1];

    // 64 threads each resolve one t: seg = searchsorted(cum, t, right), pos = t - start[seg].
    if (tid < TCHUNK) {
        int t = t0 + tid;
        int p = -1;
        if (t < T && t < total) {
            int lo = 0, hi = PN;            // first index with cum[idx] > t
            while (lo < hi) {
                int mid = (lo + hi) >> 1;
                if (cum[mid] <= t) lo = mid + 1; else hi = mid;
            }
            int seg = lo < (PN - 1) ? lo : (PN - 1);
            p = t - (cum[seg] - xs[seg]);   // within-segment position, < 64
        }
        posArr[tid] = p;
    }
    __syncthreads();

    // Stream the output: 64 t-rows x 128 float4 each = 8192 float4 per block.
    // 256 threads -> 32 iterations, fully coalesced 16B nontemporal stores
    // (output is write-only; keep it out of L2 so the pe gather stays resident).
    const f32x4* __restrict__ pe4  = (const f32x4*)pe;
    f32x4*       __restrict__ out4 = (f32x4*)out;
    const long long baseOut = ((long long)b * T + t0) * (long long)PD4;

    #pragma unroll 4
    for (int it = 0; it < 32; ++it) {
        int idx  = it * 256 + tid;          // 0..8191
        int tl   = idx >> 7;                // local t (0..63)
        int lane = idx & 127;               // float4 lane within the row
        int t = t0 + tl;
        if (t < T) {
            int p = posArr[tl];
            f32x4 val;
            if (p >= 0) {
                val = pe4[(long long)p * PD4 + lane];   // pos < 64: 128KB hot set, L2-resident
            } else {
                val = (f32x4)(0.f);                     // zero-pad (harness poisons d_out)
            }
            __builtin_nontemporal_store(val, &out4[baseOut + idx]);
        }
    }
}

extern "C" void kernel_launch(void* const* d_in, const int* in_sizes, int n_in,
                              void* d_out, int out_size, void* d_ws, size_t ws_size,
                              hipStream_t stream) {
    const int*   x  = (const int*)d_in[0];     // (B, N) int32
    const float* pe = (const float*)d_in[1];   // (MAX_LEN, D) float32
    float*       out = (float*)d_out;          // (B, T, D) float32

    // T is data-dependent but fixed per harness setup; recover from out_size.
    const int T = out_size / (PB * PD);

    dim3 grid((T + TCHUNK - 1) / TCHUNK, PB);
    dim3 block(256);
    posenc_kernel<<<grid, block, 0, stream>>>(x, pe, out, T);
}